// Round 5
// baseline (163.120 us; speedup 1.0000x reference)
//
#include <hip/hip_runtime.h>

// Sizes (fixed by the problem)
#define NB 16
#define NQ 128
#define NK 512
#define NH 128
#define NDV 128

typedef __attribute__((ext_vector_type(8))) short short8;
typedef __attribute__((ext_vector_type(4))) float f32x4;
typedef __attribute__((ext_vector_type(2))) float f32x2;

#define C2LOG2E 2.8853900817779268f  // 2*log2(e): folded into proj epilogue
#define LOG2E   1.4426950408889634f

__device__ __forceinline__ short f2bf(float x) {   // RNE f32 -> bf16
    unsigned u = __float_as_uint(x);
    unsigned r = (u + 0x7fffu + ((u >> 16) & 1u)) >> 16;
    return (short)r;
}
__device__ __forceinline__ float bf2f(short s) {
    return __uint_as_float(((unsigned)(unsigned short)s) << 16);
}

// ---------------------------------------------------------------------------
// Kernel 1: pack W (fp32 128x128) into MFMA B-fragment order, split bf16
// hi/lo. Layout: frag[((ht*4+ks)*64+lane)*8 + j] = W[ks*32+quad*8+j][ht*16+m]
// so proj reads perfectly coalesced short8. Also emits w2 = 2*wv.
// ---------------------------------------------------------------------------
__global__ __launch_bounds__(256) void wsplit_kernel(
    const float* __restrict__ Wq, const float* __restrict__ Wk,
    const float* __restrict__ wv,
    short* __restrict__ pqh, short* __restrict__ pql,
    short* __restrict__ pkh, short* __restrict__ pkl,
    float* __restrict__ w2)
{
    int blk = blockIdx.x;          // 16 blocks = w(2) x ht(8)
    int t   = threadIdx.x;         // ks(4) x lane(64)
    if (blk == 0 && t < NH) w2[t] = 2.0f * wv[t];
    int w = blk >> 3, ht = blk & 7;
    int ks = t >> 6, lane = t & 63;
    int m = lane & 15, quad = lane >> 4;
    const float* W = w ? Wk : Wq;
    short* ph = w ? pkh : pqh;
    short* pl = w ? pkl : pql;
    short8 hi, lo;
#pragma unroll
    for (int j = 0; j < 8; ++j) {
        float x = W[(size_t)(ks * 32 + quad * 8 + j) * NH + ht * 16 + m];
        short h = f2bf(x);
        hi[j] = h;
        lo[j] = f2bf(x - bf2f(h));
    }
    size_t o = (size_t)((ht * 4 + ks) * 64 + lane) * 8;
    *(short8*)(ph + o) = hi;
    *(short8*)(pl + o) = lo;
}

// ---------------------------------------------------------------------------
// Kernel 2: projection + exp. E = exp2(2log2e * X@W) via split-bf16 MFMA
// (Ah*Bh + Al*Bh + Ah*Bl, rel err ~2^-16). One wave per block, 16 rows each,
// no LDS, no barriers; B-fragments are coalesced dwordx4 from packed W.
// Blocks [0,128) -> Eq, [128,640) -> Ek.
// ---------------------------------------------------------------------------
__global__ __launch_bounds__(64) void proj_kernel(
    const float* __restrict__ Xq, const float* __restrict__ Xk,
    const short* __restrict__ pqh, const short* __restrict__ pql,
    const short* __restrict__ pkh, const short* __restrict__ pkl,
    float* __restrict__ Eq, float* __restrict__ Ek)
{
    int blk = blockIdx.x;
    const float* X; const short* ph; const short* pl; float* Y; int row0;
    if (blk < 128) { X = Xq; ph = pqh; pl = pql; Y = Eq; row0 = blk * 16; }
    else           { X = Xk; ph = pkh; pl = pkl; Y = Ek; row0 = (blk - 128) * 16; }
    int lane = threadIdx.x;
    int m = lane & 15, quad = lane >> 4;

    // A-fragments: 16 rows x K=128 (A[m][k], k = ks*32 + quad*8 + j)
    short8 AH[4], AL[4];
    const float* xr = X + (size_t)(row0 + m) * NH + quad * 8;
#pragma unroll
    for (int ks = 0; ks < 4; ++ks) {
#pragma unroll
        for (int j = 0; j < 8; ++j) {
            float x = xr[ks * 32 + j];
            short h = f2bf(x);
            AH[ks][j] = h;
            AL[ks][j] = f2bf(x - bf2f(h));
        }
    }
#pragma unroll
    for (int ht = 0; ht < 8; ++ht) {
        f32x4 acc = {0.f, 0.f, 0.f, 0.f};
#pragma unroll
        for (int ks = 0; ks < 4; ++ks) {
            size_t o = (size_t)((ht * 4 + ks) * 64 + lane) * 8;
            short8 bh = *(const short8*)(ph + o);
            short8 bl = *(const short8*)(pl + o);
            acc = __builtin_amdgcn_mfma_f32_16x16x32_bf16(AH[ks], bl, acc, 0, 0, 0);
            acc = __builtin_amdgcn_mfma_f32_16x16x32_bf16(AL[ks], bh, acc, 0, 0, 0);
            acc = __builtin_amdgcn_mfma_f32_16x16x32_bf16(AH[ks], bh, acc, 0, 0, 0);
        }
        // D: col = lane&15, row = quad*4 + r  [verified layout]
#pragma unroll
        for (int r = 0; r < 4; ++r)
            Y[(size_t)(row0 + quad * 4 + r) * NH + ht * 16 + m] =
                __builtin_amdgcn_exp2f(acc[r] * C2LOG2E);
    }
}

// ---------------------------------------------------------------------------
// Kernel 3: scores. Grid (b, q-tile4, k-chunk128) = 2048 blocks -> full
// occupancy, no serial chunk loop, no barriers in the hot loop.
// wave=q, lane covers 2 k's. Ek read direct from L1/L2 (all 4 waves share
// the same rows). p = exp(score) written to P; masked k -> exact 0.
// No max-subtraction: |score| <= sum|wv| ~ 9 -> exp is fp32-safe.
// ---------------------------------------------------------------------------
__global__ __launch_bounds__(256) void score_kernel(
    const float* __restrict__ Eq, const float* __restrict__ Ek,
    const int* __restrict__ vlen, const float* __restrict__ w2,
    float* __restrict__ P)
{
    __shared__ float s_qw[4 * NH * 2];   // (eq,w2) pairs per q: 4 KB

    int blk = blockIdx.x;
    int b  = blk & 15;                   // batch-interleaved: tail balance
    int r  = blk >> 4;
    int qt = r & 31, kc = r >> 5;
    int q0 = qt * 4, k0 = kc * 128;
    int t  = threadIdx.x;

    int nv = vlen[b];
    nv = max(1, min(NK, nv));
    float* Pb = P + ((size_t)b * NQ + q0) * NK;

    if (k0 >= nv) {                      // fully masked chunk: zeros, done
        int i = t;                       // 256 pairs = 4q x 128k
        int q = i >> 6, k = (i & 63) * 2;
        f32x2 z = {0.f, 0.f};
        *(f32x2*)&Pb[(size_t)q * NK + k0 + k] = z;
        return;
    }

    for (int i = t; i < 4 * NH; i += 256) {
        int q = i >> 7, h = i & 127;
        s_qw[i * 2]     = Eq[((size_t)b * NQ + q0 + q) * NH + h];
        s_qw[i * 2 + 1] = w2[h];
    }
    __syncthreads();

    int lane = t & 63, w = t >> 6;       // wave -> q

    // Wsum = sum_h wv = 0.5 * sum_h w2
    float s2 = w2[lane] + w2[lane + 64];
#pragma unroll
    for (int off = 32; off; off >>= 1) s2 += __shfl_xor(s2, off);
    float wsum = 0.5f * s2;

    int k1 = k0 + lane, k2 = k0 + 64 + lane;
    const float* e1 = Ek + ((size_t)b * NK + k1) * NH;
    const float* e2 = Ek + ((size_t)b * NK + k2) * NH;
    const float* qw = &s_qw[w * NH * 2];

    float a0 = 0.f, a1 = 0.f, a2 = 0.f, a3 = 0.f;
    float a4 = 0.f, a5 = 0.f, a6 = 0.f, a7 = 0.f;
#pragma unroll 4
    for (int h = 0; h < NH; h += 4) {
        f32x4 x1 = *(const f32x4*)(e1 + h);
        f32x4 x2 = *(const f32x4*)(e2 + h);
        f32x4 p0 = *(const f32x4*)(qw + h * 2);       // eq,w2 for h,h+1
        f32x4 p1 = *(const f32x4*)(qw + h * 2 + 4);   // eq,w2 for h+2,h+3
        a0 = fmaf(p0[1], __builtin_amdgcn_rcpf(fmaf(p0[0], x1[0], 1.0f)), a0);
        a1 = fmaf(p0[3], __builtin_amdgcn_rcpf(fmaf(p0[2], x1[1], 1.0f)), a1);
        a2 = fmaf(p1[1], __builtin_amdgcn_rcpf(fmaf(p1[0], x1[2], 1.0f)), a2);
        a3 = fmaf(p1[3], __builtin_amdgcn_rcpf(fmaf(p1[2], x1[3], 1.0f)), a3);
        a4 = fmaf(p0[1], __builtin_amdgcn_rcpf(fmaf(p0[0], x2[0], 1.0f)), a4);
        a5 = fmaf(p0[3], __builtin_amdgcn_rcpf(fmaf(p0[2], x2[1], 1.0f)), a5);
        a6 = fmaf(p1[1], __builtin_amdgcn_rcpf(fmaf(p1[0], x2[2], 1.0f)), a6);
        a7 = fmaf(p1[3], __builtin_amdgcn_rcpf(fmaf(p1[2], x2[3], 1.0f)), a7);
    }
    float sc1 = wsum - ((a0 + a1) + (a2 + a3));
    float sc2 = wsum - ((a4 + a5) + (a6 + a7));
    float pp1 = (k1 < nv) ? __builtin_amdgcn_exp2f(sc1 * LOG2E) : 0.f;
    float pp2 = (k2 < nv) ? __builtin_amdgcn_exp2f(sc2 * LOG2E) : 0.f;
    Pb[(size_t)w * NK + k1] = pp1;       // coalesced dword stores
    Pb[(size_t)w * NK + k2] = pp2;
}

// ---------------------------------------------------------------------------
// Kernel 4: softmax-normalize + AV. Block = (b, q-tile4); wave=q, lane=dv
// pair. P rows staged coalesced into LDS; sum includes exact zeros beyond
// nv; V loads 8-deep independent.
// ---------------------------------------------------------------------------
__global__ __launch_bounds__(256) void av_kernel(
    const float* __restrict__ P, const float* __restrict__ V,
    const int* __restrict__ vlen, float* __restrict__ out)
{
    __shared__ float s_p[4 * NK];        // 8 KB

    int blk = blockIdx.x;
    int b = blk & 15, qt = blk >> 4;
    int q0 = qt * 4;
    int t = threadIdx.x;

    int nv = vlen[b];
    nv = max(1, min(NK, nv));

    const f32x4* Pv = (const f32x4*)(P + ((size_t)b * NQ + q0) * NK);
    ((f32x4*)s_p)[t]       = Pv[t];
    ((f32x4*)s_p)[t + 256] = Pv[t + 256];
    __syncthreads();

    int lane = t & 63, w = t >> 6;
    const float* pr = &s_p[w * NK];

    float sm = 0.f;
    f32x4 u0 = *(const f32x4*)(pr + lane * 8);
    f32x4 u1 = *(const f32x4*)(pr + lane * 8 + 4);
    sm = ((u0[0] + u0[1]) + (u0[2] + u0[3])) + ((u1[0] + u1[1]) + (u1[2] + u1[3]));
#pragma unroll
    for (int off = 32; off; off >>= 1) sm += __shfl_xor(sm, off);
    float rinv = 1.0f / sm;

    int dv0 = lane * 2;
    const float* Vb = V + (size_t)b * NK * NDV + dv0;
    float o0 = 0.f, o1 = 0.f;
    int k = 0;
    for (; k + 8 <= nv; k += 8) {
        f32x4 pA = *(const f32x4*)(pr + k);          // LDS broadcast
        f32x4 pB = *(const f32x4*)(pr + k + 4);
        f32x2 v0 = *(const f32x2*)(Vb + (size_t)(k + 0) * NDV);
        f32x2 v1 = *(const f32x2*)(Vb + (size_t)(k + 1) * NDV);
        f32x2 v2 = *(const f32x2*)(Vb + (size_t)(k + 2) * NDV);
        f32x2 v3 = *(const f32x2*)(Vb + (size_t)(k + 3) * NDV);
        f32x2 v4 = *(const f32x2*)(Vb + (size_t)(k + 4) * NDV);
        f32x2 v5 = *(const f32x2*)(Vb + (size_t)(k + 5) * NDV);
        f32x2 v6 = *(const f32x2*)(Vb + (size_t)(k + 6) * NDV);
        f32x2 v7 = *(const f32x2*)(Vb + (size_t)(k + 7) * NDV);
        o0 = fmaf(pA[0], v0[0], o0); o1 = fmaf(pA[0], v0[1], o1);
        o0 = fmaf(pA[1], v1[0], o0); o1 = fmaf(pA[1], v1[1], o1);
        o0 = fmaf(pA[2], v2[0], o0); o1 = fmaf(pA[2], v2[1], o1);
        o0 = fmaf(pA[3], v3[0], o0); o1 = fmaf(pA[3], v3[1], o1);
        o0 = fmaf(pB[0], v4[0], o0); o1 = fmaf(pB[0], v4[1], o1);
        o0 = fmaf(pB[1], v5[0], o0); o1 = fmaf(pB[1], v5[1], o1);
        o0 = fmaf(pB[2], v6[0], o0); o1 = fmaf(pB[2], v6[1], o1);
        o0 = fmaf(pB[3], v7[0], o0); o1 = fmaf(pB[3], v7[1], o1);
    }
    for (; k < nv; ++k) {
        float p = pr[k];
        f32x2 v = *(const f32x2*)(Vb + (size_t)k * NDV);
        o0 = fmaf(p, v[0], o0);
        o1 = fmaf(p, v[1], o1);
    }
    size_t ob = ((size_t)b * NQ + q0 + w) * NDV + dv0;
    f32x2 o = {o0 * rinv, o1 * rinv};
    *(f32x2*)&out[ob] = o;
}

extern "C" void kernel_launch(void* const* d_in, const int* in_sizes, int n_in,
                              void* d_out, int out_size, void* d_ws, size_t ws_size,
                              hipStream_t stream) {
    const float* q  = (const float*)d_in[0];  // (16,128,128) f32
    const float* ks = (const float*)d_in[1];  // (16,512,128) f32
    const float* vs = (const float*)d_in[2];  // (16,512,128) f32
    const int*   vl = (const int*)d_in[3];    // (16,) i32
    const float* wq = (const float*)d_in[4];  // (128,128) f32
    const float* wk = (const float*)d_in[5];  // (128,128) f32
    const float* wv = (const float*)d_in[6];  // (128,) f32

    // ws layout (~9.2 MB)
    float* Eq = (float*)d_ws;                     // 2048*128
    float* Ek = Eq + 2048 * 128;                  // 8192*128
    float* P  = Ek + (size_t)8192 * 128;          // 16*128*512
    float* w2 = P + (size_t)NB * NQ * NK;         // 128
    short* pqh = (short*)(w2 + 128);              // 4 x 16384 bf16 frags
    short* pql = pqh + 16384;
    short* pkh = pql + 16384;
    short* pkl = pkh + 16384;

    wsplit_kernel<<<16, 256, 0, stream>>>(wq, wk, wv, pqh, pql, pkh, pkl, w2);
    proj_kernel<<<640, 64, 0, stream>>>(q, ks, pqh, pql, pkh, pkl, Eq, Ek);
    score_kernel<<<2048, 256, 0, stream>>>(Eq, Ek, vl, w2, P);
    av_kernel<<<512, 256, 0, stream>>>(P, vs, vl, (float*)d_out);
}

// Round 7
// 118.933 us; speedup vs baseline: 1.3715x; 1.3715x over previous
//
#include <hip/hip_runtime.h>

// Sizes (fixed by the problem)
#define NB 16
#define NQ 128
#define NK 512
#define NH 128
#define NDV 128

#define KPAD 132  // 128+4 floats: b128 lane*KPAD reads measured 0 conflicts

typedef __attribute__((ext_vector_type(8))) short short8;
typedef __attribute__((ext_vector_type(4))) float f32x4;
typedef __attribute__((ext_vector_type(2))) float f32x2;

#define C2LOG2E 2.8853900817779268f  // 2*log2(e): folded into proj epilogue
#define LOG2E   1.4426950408889634f

__device__ __forceinline__ short f2bf(float x) {   // RNE f32 -> bf16
    unsigned u = __float_as_uint(x);
    unsigned r = (u + 0x7fffu + ((u >> 16) & 1u)) >> 16;
    return (short)r;
}
__device__ __forceinline__ float bf2f(short s) {
    return __uint_as_float(((unsigned)(unsigned short)s) << 16);
}

// ---------------------------------------------------------------------------
// Kernel 1: pack W into MFMA B-fragment order, split bf16 hi/lo.
// frag[((ht*4+ks)*64+lane)*8 + j] = W[ks*32+quad*8+j][ht*16+m]. Also w2=2*wv.
// ---------------------------------------------------------------------------
__global__ __launch_bounds__(256) void wsplit_kernel(
    const float* __restrict__ Wq, const float* __restrict__ Wk,
    const float* __restrict__ wv,
    short* __restrict__ pqh, short* __restrict__ pql,
    short* __restrict__ pkh, short* __restrict__ pkl,
    float* __restrict__ w2)
{
    int blk = blockIdx.x;          // 16 blocks = w(2) x ht(8)
    int t   = threadIdx.x;         // ks(4) x lane(64)
    if (blk == 0 && t < NH) w2[t] = 2.0f * wv[t];
    int w = blk >> 3, ht = blk & 7;
    int ks = t >> 6, lane = t & 63;
    int m = lane & 15, quad = lane >> 4;
    const float* W = w ? Wk : Wq;
    short* ph = w ? pkh : pqh;
    short* pl = w ? pkl : pql;
    short8 hi, lo;
#pragma unroll
    for (int j = 0; j < 8; ++j) {
        float x = W[(size_t)(ks * 32 + quad * 8 + j) * NH + ht * 16 + m];
        short h = f2bf(x);
        hi[j] = h;
        lo[j] = f2bf(x - bf2f(h));
    }
    size_t o = (size_t)((ht * 4 + ks) * 64 + lane) * 8;
    *(short8*)(ph + o) = hi;
    *(short8*)(pl + o) = lo;
}

// ---------------------------------------------------------------------------
// Kernel 2: projection + exp. E = exp2(2log2e * X@W), split-bf16 MFMA.
// Block = 256 thr (4 waves) on ONE 16-row tile; wave w does h-tiles 2w,2w+1.
// 2560 waves total. B-frags coalesced b128 from packed W.
// Blocks [0,128) -> Eq, [128,640) -> Ek.
// ---------------------------------------------------------------------------
__global__ __launch_bounds__(256) void proj_kernel(
    const float* __restrict__ Xq, const float* __restrict__ Xk,
    const short* __restrict__ pqh, const short* __restrict__ pql,
    const short* __restrict__ pkh, const short* __restrict__ pkl,
    float* __restrict__ Eq, float* __restrict__ Ek)
{
    int blk = blockIdx.x;
    const float* X; const short* ph; const short* pl; float* Y; int row0;
    if (blk < 128) { X = Xq; ph = pqh; pl = pql; Y = Eq; row0 = blk * 16; }
    else           { X = Xk; ph = pkh; pl = pkl; Y = Ek; row0 = (blk - 128) * 16; }
    int t = threadIdx.x;
    int wave = t >> 6, lane = t & 63;
    int m = lane & 15, quad = lane >> 4;

    // A-fragments: 16 rows x K=128 (A[m][k], k = ks*32 + quad*8 + j)
    short8 AH[4], AL[4];
    const float* xr = X + (size_t)(row0 + m) * NH + quad * 8;
#pragma unroll
    for (int ks = 0; ks < 4; ++ks) {
#pragma unroll
        for (int j = 0; j < 8; ++j) {
            float x = xr[ks * 32 + j];
            short h = f2bf(x);
            AH[ks][j] = h;
            AL[ks][j] = f2bf(x - bf2f(h));
        }
    }
#pragma unroll
    for (int hi = 0; hi < 2; ++hi) {
        int ht = wave * 2 + hi;
        f32x4 acc = {0.f, 0.f, 0.f, 0.f};
#pragma unroll
        for (int ks = 0; ks < 4; ++ks) {
            size_t o = (size_t)((ht * 4 + ks) * 64 + lane) * 8;
            short8 bh = *(const short8*)(ph + o);
            short8 bl = *(const short8*)(pl + o);
            acc = __builtin_amdgcn_mfma_f32_16x16x32_bf16(AH[ks], bl, acc, 0, 0, 0);
            acc = __builtin_amdgcn_mfma_f32_16x16x32_bf16(AL[ks], bh, acc, 0, 0, 0);
            acc = __builtin_amdgcn_mfma_f32_16x16x32_bf16(AH[ks], bh, acc, 0, 0, 0);
        }
        // D: col = lane&15, row = quad*4 + r  [verified layout]
#pragma unroll
        for (int r = 0; r < 4; ++r)
            Y[(size_t)(row0 + quad * 4 + r) * NH + ht * 16 + m] =
                __builtin_amdgcn_exp2f(acc[r] * C2LOG2E);
    }
}

// ---------------------------------------------------------------------------
// Kernel 3: scores. Block = (b, 8-q tile, 128-k chunk) = 1024 blocks x 512thr.
// Ek chunk staged COALESCED into LDS once (1 barrier); wave=q, lane covers
// k=lane and k=lane+64. p = exp(score) -> P; masked k -> exact 0.
// |score| <= sum|wv| ~ 9 so exp is fp32-safe without max-subtraction.
// ---------------------------------------------------------------------------
__global__ __launch_bounds__(512) void score_kernel(
    const float* __restrict__ Eqp, const float* __restrict__ Ekp,
    const int* __restrict__ vlen, const float* __restrict__ w2,
    float* __restrict__ P)
{
    __shared__ float s_ek[128 * KPAD];   // 67584 B
    __shared__ float s_qw[8 * NH * 2];   //  8192 B  (eq,w2 pairs per q)

    int blk = blockIdx.x;
    int b    = blk & 15;                 // batch-interleaved: tail balance
    int rest = blk >> 4;
    int qt = rest & 15, kc = rest >> 4;  // qt 0..15 (8q each), kc 0..3 (128k)
    int q0 = qt * 8, k0 = kc * 128;
    int t  = threadIdx.x;

    int nv = vlen[b];
    nv = max(1, min(NK, nv));
    float* Pb = P + ((size_t)b * NQ + q0) * NK;

    if (k0 >= nv) {
        // fully masked chunk: exactly 8q x 128k = 512 f32x2, one per thread.
        // (round-6 bug: wrote 2x this extent, clobbering neighbor tiles)
        int q = t >> 6, kk = (t & 63) * 2;
        f32x2 z = {0.f, 0.f};
        *(f32x2*)&Pb[(size_t)q * NK + k0 + kk] = z;
        return;
    }

    // stage Ek chunk coalesced + (eq,w2) pair rows
    for (int i = t; i < 128 * 32; i += 512) {
        int row = i >> 5, c4 = i & 31;
        *(f32x4*)&s_ek[row * KPAD + c4 * 4] =
            *(const f32x4*)&Ekp[((size_t)b * NK + k0 + row) * NH + c4 * 4];
    }
    for (int i = t; i < 8 * NH; i += 512) {
        int q = i >> 7, h = i & 127;
        s_qw[i * 2]     = Eqp[((size_t)b * NQ + q0 + q) * NH + h];
        s_qw[i * 2 + 1] = w2[h];
    }
    __syncthreads();

    int lane = t & 63, wave = t >> 6;    // wave -> q

    // Wsum = sum_h wv = 0.5 * sum_h w2
    float s2 = w2[lane] + w2[lane + 64];
#pragma unroll
    for (int off = 32; off; off >>= 1) s2 += __shfl_xor(s2, off);
    float wsum = 0.5f * s2;

    const float* e1 = &s_ek[lane * KPAD];
    const float* e2 = &s_ek[(lane + 64) * KPAD];
    const float* qw = &s_qw[wave * NH * 2];

    float c0 = 0.f, c1 = 0.f, c2 = 0.f, c3 = 0.f;   // k1 chains
    float c4 = 0.f, c5 = 0.f, c6 = 0.f, c7 = 0.f;   // k2 chains
#pragma unroll
    for (int hh = 0; hh < NH; hh += 8) {
        f32x4 p0 = *(const f32x4*)(qw + hh * 2);      // eq,w2 for hh,hh+1
        f32x4 p1 = *(const f32x4*)(qw + hh * 2 + 4);
        f32x4 p2 = *(const f32x4*)(qw + hh * 2 + 8);
        f32x4 p3 = *(const f32x4*)(qw + hh * 2 + 12);
        f32x4 kA = *(const f32x4*)(e1 + hh);
        f32x4 kB = *(const f32x4*)(e1 + hh + 4);
        f32x4 kC = *(const f32x4*)(e2 + hh);
        f32x4 kD = *(const f32x4*)(e2 + hh + 4);
        c0 = fmaf(p0[1], __builtin_amdgcn_rcpf(fmaf(p0[0], kA[0], 1.0f)), c0);
        c1 = fmaf(p0[3], __builtin_amdgcn_rcpf(fmaf(p0[2], kA[1], 1.0f)), c1);
        c2 = fmaf(p1[1], __builtin_amdgcn_rcpf(fmaf(p1[0], kA[2], 1.0f)), c2);
        c3 = fmaf(p1[3], __builtin_amdgcn_rcpf(fmaf(p1[2], kA[3], 1.0f)), c3);
        c4 = fmaf(p0[1], __builtin_amdgcn_rcpf(fmaf(p0[0], kC[0], 1.0f)), c4);
        c5 = fmaf(p0[3], __builtin_amdgcn_rcpf(fmaf(p0[2], kC[1], 1.0f)), c5);
        c6 = fmaf(p1[1], __builtin_amdgcn_rcpf(fmaf(p1[0], kC[2], 1.0f)), c6);
        c7 = fmaf(p1[3], __builtin_amdgcn_rcpf(fmaf(p1[2], kC[3], 1.0f)), c7);
        c0 = fmaf(p2[1], __builtin_amdgcn_rcpf(fmaf(p2[0], kB[0], 1.0f)), c0);
        c1 = fmaf(p2[3], __builtin_amdgcn_rcpf(fmaf(p2[2], kB[1], 1.0f)), c1);
        c2 = fmaf(p3[1], __builtin_amdgcn_rcpf(fmaf(p3[0], kB[2], 1.0f)), c2);
        c3 = fmaf(p3[3], __builtin_amdgcn_rcpf(fmaf(p3[2], kB[3], 1.0f)), c3);
        c4 = fmaf(p2[1], __builtin_amdgcn_rcpf(fmaf(p2[0], kD[0], 1.0f)), c4);
        c5 = fmaf(p2[3], __builtin_amdgcn_rcpf(fmaf(p2[2], kD[1], 1.0f)), c5);
        c6 = fmaf(p3[1], __builtin_amdgcn_rcpf(fmaf(p3[0], kD[2], 1.0f)), c6);
        c7 = fmaf(p3[3], __builtin_amdgcn_rcpf(fmaf(p3[2], kD[3], 1.0f)), c7);
    }
    float sc1 = wsum - ((c0 + c1) + (c2 + c3));
    float sc2 = wsum - ((c4 + c5) + (c6 + c7));
    int k1 = k0 + lane, k2 = k0 + 64 + lane;
    float pp1 = (k1 < nv) ? __builtin_amdgcn_exp2f(sc1 * LOG2E) : 0.f;
    float pp2 = (k2 < nv) ? __builtin_amdgcn_exp2f(sc2 * LOG2E) : 0.f;
    float* Pr = Pb + (size_t)wave * NK;
    Pr[k1] = pp1;                        // coalesced dword stores
    Pr[k2] = pp2;
}

// ---------------------------------------------------------------------------
// Kernel 4: normalize + AV. Block = (b, 4-q tile) x 512 thr: waves 0-3 own
// k[0,256) for q=w, waves 4-7 own k[256,512). Partial O reduced via LDS.
// ---------------------------------------------------------------------------
__global__ __launch_bounds__(512) void av_kernel(
    const float* __restrict__ P, const float* __restrict__ V,
    const int* __restrict__ vlen, float* __restrict__ out)
{
    __shared__ float s_p[4 * NK];        //  8 KB
    __shared__ float s_red[8 * 64 * 2];  //  4 KB partial O
    __shared__ float s_sum[8];

    int blk = blockIdx.x;
    int b = blk & 15, qt = blk >> 4;     // qt 0..31
    int q0 = qt * 4;
    int t = threadIdx.x;

    int nv = vlen[b];
    nv = max(1, min(NK, nv));

    const f32x4* Pv = (const f32x4*)(P + ((size_t)b * NQ + q0) * NK);
    ((f32x4*)s_p)[t] = Pv[t];            // 512 f32x4 = 4q x 512k
    __syncthreads();

    int lane = t & 63, w = t >> 6;
    int q = w & 3, half = w >> 2;
    int kbeg = half * 256, kend = min(nv, kbeg + 256);
    const float* pr = &s_p[q * NK];

    // partial sum over this wave's half (256 floats: 4/lane)
    f32x4 u = *(const f32x4*)(pr + kbeg + lane * 4);
    float sm = (u[0] + u[1]) + (u[2] + u[3]);
#pragma unroll
    for (int off = 32; off; off >>= 1) sm += __shfl_xor(sm, off);
    if (lane == 0) s_sum[w] = sm;

    int dv0 = lane * 2;
    const float* Vb = V + (size_t)b * NK * NDV + dv0;
    float o0 = 0.f, o1 = 0.f;
    int k = kbeg;
    for (; k + 8 <= kend; k += 8) {
        f32x4 pA = *(const f32x4*)(pr + k);          // LDS broadcast
        f32x4 pB = *(const f32x4*)(pr + k + 4);
        f32x2 v0 = *(const f32x2*)(Vb + (size_t)(k + 0) * NDV);
        f32x2 v1 = *(const f32x2*)(Vb + (size_t)(k + 1) * NDV);
        f32x2 v2 = *(const f32x2*)(Vb + (size_t)(k + 2) * NDV);
        f32x2 v3 = *(const f32x2*)(Vb + (size_t)(k + 3) * NDV);
        f32x2 v4 = *(const f32x2*)(Vb + (size_t)(k + 4) * NDV);
        f32x2 v5 = *(const f32x2*)(Vb + (size_t)(k + 5) * NDV);
        f32x2 v6 = *(const f32x2*)(Vb + (size_t)(k + 6) * NDV);
        f32x2 v7 = *(const f32x2*)(Vb + (size_t)(k + 7) * NDV);
        o0 = fmaf(pA[0], v0[0], o0); o1 = fmaf(pA[0], v0[1], o1);
        o0 = fmaf(pA[1], v1[0], o0); o1 = fmaf(pA[1], v1[1], o1);
        o0 = fmaf(pA[2], v2[0], o0); o1 = fmaf(pA[2], v2[1], o1);
        o0 = fmaf(pA[3], v3[0], o0); o1 = fmaf(pA[3], v3[1], o1);
        o0 = fmaf(pB[0], v4[0], o0); o1 = fmaf(pB[0], v4[1], o1);
        o0 = fmaf(pB[1], v5[0], o0); o1 = fmaf(pB[1], v5[1], o1);
        o0 = fmaf(pB[2], v6[0], o0); o1 = fmaf(pB[2], v6[1], o1);
        o0 = fmaf(pB[3], v7[0], o0); o1 = fmaf(pB[3], v7[1], o1);
    }
    for (; k < kend; ++k) {
        float p = pr[k];
        f32x2 v = *(const f32x2*)(Vb + (size_t)k * NDV);
        o0 = fmaf(p, v[0], o0);
        o1 = fmaf(p, v[1], o1);
    }
    f32x2 po = {o0, o1};
    *(f32x2*)&s_red[(w * 64 + lane) * 2] = po;
    __syncthreads();

    if (w < 4) {
        f32x2 x0 = *(const f32x2*)&s_red[(w * 64 + lane) * 2];
        f32x2 x1 = *(const f32x2*)&s_red[((w + 4) * 64 + lane) * 2];
        float rinv = 1.0f / (s_sum[w] + s_sum[w + 4]);
        size_t ob = ((size_t)b * NQ + q0 + w) * NDV + dv0;
        f32x2 o = {(x0[0] + x1[0]) * rinv, (x0[1] + x1[1]) * rinv};
        *(f32x2*)&out[ob] = o;
    }
}

extern "C" void kernel_launch(void* const* d_in, const int* in_sizes, int n_in,
                              void* d_out, int out_size, void* d_ws, size_t ws_size,
                              hipStream_t stream) {
    const float* q  = (const float*)d_in[0];  // (16,128,128) f32
    const float* ks = (const float*)d_in[1];  // (16,512,128) f32
    const float* vs = (const float*)d_in[2];  // (16,512,128) f32
    const int*   vl = (const int*)d_in[3];    // (16,) i32
    const float* wq = (const float*)d_in[4];  // (128,128) f32
    const float* wk = (const float*)d_in[5];  // (128,128) f32
    const float* wv = (const float*)d_in[6];  // (128,) f32

    // ws layout (~9.3 MB)
    float* Eq = (float*)d_ws;                     // 2048*128
    float* Ek = Eq + 2048 * 128;                  // 8192*128
    float* P  = Ek + (size_t)8192 * 128;          // 16*128*512
    float* w2 = P + (size_t)NB * NQ * NK;         // 128
    short* pqh = (short*)(w2 + 128);              // 4 x 16384 bf16 frags
    short* pql = pqh + 16384;
    short* pkh = pql + 16384;
    short* pkl = pkh + 16384;

    wsplit_kernel<<<16, 256, 0, stream>>>(wq, wk, wv, pqh, pql, pkh, pkl, w2);
    proj_kernel<<<640, 256, 0, stream>>>(q, ks, pqh, pql, pkh, pkl, Eq, Ek);
    score_kernel<<<1024, 512, 0, stream>>>(Eq, Ek, vl, w2, P);
    av_kernel<<<512, 512, 0, stream>>>(P, vs, vl, (float*)d_out);
}

// Round 8
// 107.943 us; speedup vs baseline: 1.5112x; 1.1018x over previous
//
#include <hip/hip_runtime.h>

// Sizes (fixed by the problem)
#define NB 16
#define NQ 128
#define NK 512
#define NH 128
#define NDV 128

#define KPAD 132  // 128+4 floats: b128 lane*KPAD reads measured 0 conflicts

typedef __attribute__((ext_vector_type(8))) short short8;
typedef __attribute__((ext_vector_type(4))) float f32x4;
typedef __attribute__((ext_vector_type(2))) float f32x2;

#define C2LOG2E 2.8853900817779268f  // 2*log2(e): folded into proj epilogue
#define LOG2E   1.4426950408889634f

__device__ __forceinline__ short f2bf(float x) {   // RNE f32 -> bf16
    unsigned u = __float_as_uint(x);
    unsigned r = (u + 0x7fffu + ((u >> 16) & 1u)) >> 16;
    return (short)r;
}
__device__ __forceinline__ float bf2f(short s) {
    return __uint_as_float(((unsigned)(unsigned short)s) << 16);
}

// ---------------------------------------------------------------------------
// Kernel 1: pack W into MFMA B-fragment order, split bf16 hi/lo.
// frag[((ht*4+ks)*64+lane)*8 + j] = W[ks*32+quad*8+j][ht*16+m]. Also w2=2*wv.
// ---------------------------------------------------------------------------
__global__ __launch_bounds__(256) void wsplit_kernel(
    const float* __restrict__ Wq, const float* __restrict__ Wk,
    const float* __restrict__ wv,
    short* __restrict__ pqh, short* __restrict__ pql,
    short* __restrict__ pkh, short* __restrict__ pkl,
    float* __restrict__ w2)
{
    int blk = blockIdx.x;          // 16 blocks = w(2) x ht(8)
    int t   = threadIdx.x;         // ks(4) x lane(64)
    if (blk == 0 && t < NH) w2[t] = 2.0f * wv[t];
    int w = blk >> 3, ht = blk & 7;
    int ks = t >> 6, lane = t & 63;
    int m = lane & 15, quad = lane >> 4;
    const float* W = w ? Wk : Wq;
    short* ph = w ? pkh : pqh;
    short* pl = w ? pkl : pql;
    short8 hi, lo;
#pragma unroll
    for (int j = 0; j < 8; ++j) {
        float x = W[(size_t)(ks * 32 + quad * 8 + j) * NH + ht * 16 + m];
        short h = f2bf(x);
        hi[j] = h;
        lo[j] = f2bf(x - bf2f(h));
    }
    size_t o = (size_t)((ht * 4 + ks) * 64 + lane) * 8;
    *(short8*)(ph + o) = hi;
    *(short8*)(pl + o) = lo;
}

// ---------------------------------------------------------------------------
// Kernel 2: projection + exp. E = exp2(2log2e * X@W), split-bf16 MFMA.
// X tile (16 rows) staged ONCE per block into LDS (coalesced), then all 4
// waves read A-frags as b128 (was: 4x redundant scattered dword VMEM).
// Wave w computes h-tiles 2w, 2w+1. Blocks [0,128) -> Eq, [128,640) -> Ek.
// ---------------------------------------------------------------------------
__global__ __launch_bounds__(256) void proj_kernel(
    const float* __restrict__ Xq, const float* __restrict__ Xk,
    const short* __restrict__ pqh, const short* __restrict__ pql,
    const short* __restrict__ pkh, const short* __restrict__ pkl,
    float* __restrict__ Eq, float* __restrict__ Ek)
{
    __shared__ float s_x[16 * KPAD];     // 8448 B, pad -> 2-way (free)

    int blk = blockIdx.x;
    const float* X; const short* ph; const short* pl; float* Y; int row0;
    if (blk < 128) { X = Xq; ph = pqh; pl = pql; Y = Eq; row0 = blk * 16; }
    else           { X = Xk; ph = pkh; pl = pkl; Y = Ek; row0 = (blk - 128) * 16; }
    int t = threadIdx.x;
    int wave = t >> 6, lane = t & 63;
    int m = lane & 15, quad = lane >> 4;

    // stage X tile coalesced: 2048 floats = 512 f32x4, 2 per thread
#pragma unroll
    for (int r = 0; r < 2; ++r) {
        int i = (t + r * 256) * 4;
        int row = i >> 7, col = i & 127;
        *(f32x4*)&s_x[row * KPAD + col] =
            *(const f32x4*)&X[(size_t)(row0 + row) * NH + col];
    }
    __syncthreads();

    // A-fragments from LDS: A[m][k], k = ks*32 + quad*8 + j
    short8 AH[4], AL[4];
#pragma unroll
    for (int ks = 0; ks < 4; ++ks) {
        int base = m * KPAD + ks * 32 + quad * 8;
        f32x4 x0 = *(const f32x4*)&s_x[base];
        f32x4 x1 = *(const f32x4*)&s_x[base + 4];
#pragma unroll
        for (int j = 0; j < 4; ++j) {
            short h0 = f2bf(x0[j]);
            AH[ks][j] = h0; AL[ks][j] = f2bf(x0[j] - bf2f(h0));
            short h1 = f2bf(x1[j]);
            AH[ks][j + 4] = h1; AL[ks][j + 4] = f2bf(x1[j] - bf2f(h1));
        }
    }
#pragma unroll
    for (int hi = 0; hi < 2; ++hi) {
        int ht = wave * 2 + hi;
        f32x4 acc = {0.f, 0.f, 0.f, 0.f};
#pragma unroll
        for (int ks = 0; ks < 4; ++ks) {
            size_t o = (size_t)((ht * 4 + ks) * 64 + lane) * 8;
            short8 bh = *(const short8*)(ph + o);
            short8 bl = *(const short8*)(pl + o);
            acc = __builtin_amdgcn_mfma_f32_16x16x32_bf16(AH[ks], bl, acc, 0, 0, 0);
            acc = __builtin_amdgcn_mfma_f32_16x16x32_bf16(AL[ks], bh, acc, 0, 0, 0);
            acc = __builtin_amdgcn_mfma_f32_16x16x32_bf16(AH[ks], bh, acc, 0, 0, 0);
        }
        // D: col = lane&15, row = quad*4 + r  [verified layout]
#pragma unroll
        for (int r = 0; r < 4; ++r)
            Y[(size_t)(row0 + quad * 4 + r) * NH + ht * 16 + m] =
                __builtin_amdgcn_exp2f(acc[r] * C2LOG2E);
    }
}

// ---------------------------------------------------------------------------
// Kernel 3: scores. Block = (b, 16-q tile, 128-k chunk) = 512 blocks x 512thr.
// Wave w: q-group g=w&3 (4 q's), k-half hf=w>>2; lane owns ONE k. Each Ek
// lane-read serves 4 q -> LDS traffic /4 vs round 7; VALU(rcp) becomes limit.
// p = exp(score) -> P; masked k -> exact 0. |score|<=sum|wv|~9: exp fp32-safe.
// ---------------------------------------------------------------------------
__global__ __launch_bounds__(512) void score_kernel(
    const float* __restrict__ Eqp, const float* __restrict__ Ekp,
    const int* __restrict__ vlen, const float* __restrict__ w2,
    float* __restrict__ P)
{
    __shared__ float s_ek[128 * KPAD];   // 67584 B
    __shared__ float s_eq[16 * NH];      //  8192 B
    __shared__ float s_w2[NH];           //   512 B

    int blk = blockIdx.x;
    int b    = blk & 15;                 // batch-interleaved: tail balance
    int rest = blk >> 4;
    int qt = rest & 7, kc = rest >> 3;   // qt 0..7 (16q each), kc 0..3 (128k)
    int q0 = qt * 16, k0 = kc * 128;
    int t  = threadIdx.x;

    int nv = vlen[b];
    nv = max(1, min(NK, nv));
    float* Pb = P + ((size_t)b * NQ + q0) * NK;

    if (k0 >= nv) {
        // fully masked chunk: 16q x 128k = 2048 floats = one f32x4/thread
        int q = t >> 5, kk = (t & 31) * 4;
        f32x4 z = {0.f, 0.f, 0.f, 0.f};
        *(f32x4*)&Pb[(size_t)q * NK + k0 + kk] = z;
        return;
    }

    // stage Ek chunk (coalesced, padded), Eq tile, w2
    for (int i = t; i < 128 * 32; i += 512) {
        int row = i >> 5, c4 = i & 31;
        *(f32x4*)&s_ek[row * KPAD + c4 * 4] =
            *(const f32x4*)&Ekp[((size_t)b * NK + k0 + row) * NH + c4 * 4];
    }
    *(f32x4*)&s_eq[t * 4] =
        *(const f32x4*)&Eqp[((size_t)b * NQ + q0) * NH + t * 4];
    if (t < 32) *(f32x4*)&s_w2[t * 4] = *(const f32x4*)&w2[t * 4];
    __syncthreads();

    int lane = t & 63, w = t >> 6;
    int g = w & 3, hf = w >> 2;

    // Wsum = sum_h wv = 0.5 * sum_h w2
    float s2 = s_w2[lane] + s_w2[lane + 64];
#pragma unroll
    for (int off = 32; off; off >>= 1) s2 += __shfl_xor(s2, off);
    float wsum = 0.5f * s2;

    const float* ek = &s_ek[(hf * 64 + lane) * KPAD];
    const float* e0 = &s_eq[(g * 4 + 0) * NH];
    const float* e1 = &s_eq[(g * 4 + 1) * NH];
    const float* e2 = &s_eq[(g * 4 + 2) * NH];
    const float* e3 = &s_eq[(g * 4 + 3) * NH];

    float c00 = 0.f, c01 = 0.f, c10 = 0.f, c11 = 0.f;
    float c20 = 0.f, c21 = 0.f, c30 = 0.f, c31 = 0.f;
#pragma unroll
    for (int hh = 0; hh < NH; hh += 8) {
        f32x4 kA = *(const f32x4*)(ek + hh);
        f32x4 kB = *(const f32x4*)(ek + hh + 4);
        f32x4 wA = *(const f32x4*)(s_w2 + hh);
        f32x4 wB = *(const f32x4*)(s_w2 + hh + 4);
        f32x4 qA0 = *(const f32x4*)(e0 + hh), qB0 = *(const f32x4*)(e0 + hh + 4);
        f32x4 qA1 = *(const f32x4*)(e1 + hh), qB1 = *(const f32x4*)(e1 + hh + 4);
        f32x4 qA2 = *(const f32x4*)(e2 + hh), qB2 = *(const f32x4*)(e2 + hh + 4);
        f32x4 qA3 = *(const f32x4*)(e3 + hh), qB3 = *(const f32x4*)(e3 + hh + 4);
#pragma unroll
        for (int i = 0; i < 4; ++i) {
            c00 = fmaf(wA[i], __builtin_amdgcn_rcpf(fmaf(qA0[i], kA[i], 1.0f)), c00);
            c10 = fmaf(wA[i], __builtin_amdgcn_rcpf(fmaf(qA1[i], kA[i], 1.0f)), c10);
            c20 = fmaf(wA[i], __builtin_amdgcn_rcpf(fmaf(qA2[i], kA[i], 1.0f)), c20);
            c30 = fmaf(wA[i], __builtin_amdgcn_rcpf(fmaf(qA3[i], kA[i], 1.0f)), c30);
            c01 = fmaf(wB[i], __builtin_amdgcn_rcpf(fmaf(qB0[i], kB[i], 1.0f)), c01);
            c11 = fmaf(wB[i], __builtin_amdgcn_rcpf(fmaf(qB1[i], kB[i], 1.0f)), c11);
            c21 = fmaf(wB[i], __builtin_amdgcn_rcpf(fmaf(qB2[i], kB[i], 1.0f)), c21);
            c31 = fmaf(wB[i], __builtin_amdgcn_rcpf(fmaf(qB3[i], kB[i], 1.0f)), c31);
        }
    }
    int kg = k0 + hf * 64 + lane;
    bool valid = kg < nv;
    float p0 = valid ? __builtin_amdgcn_exp2f((wsum - (c00 + c01)) * LOG2E) : 0.f;
    float p1 = valid ? __builtin_amdgcn_exp2f((wsum - (c10 + c11)) * LOG2E) : 0.f;
    float p2 = valid ? __builtin_amdgcn_exp2f((wsum - (c20 + c21)) * LOG2E) : 0.f;
    float p3 = valid ? __builtin_amdgcn_exp2f((wsum - (c30 + c31)) * LOG2E) : 0.f;
    float* Pr = Pb + (size_t)(g * 4) * NK + kg;
    Pr[0 * NK] = p0;                     // coalesced dword stores per q-row
    Pr[1 * NK] = p1;
    Pr[2 * NK] = p2;
    Pr[3 * NK] = p3;
}

// ---------------------------------------------------------------------------
// Kernel 4: normalize + AV. Block = (b, 8-q tile) x 256 thr; wave owns 2 q
// over ALL k (no cross-wave reduction); lane owns a dv pair. P staged in LDS
// (b128 broadcasts per 4k); V f32x2 coalesced; p==0 beyond nv makes the
// 8-rounded over-read exact.
// ---------------------------------------------------------------------------
__global__ __launch_bounds__(256) void av_kernel(
    const float* __restrict__ P, const float* __restrict__ V,
    const int* __restrict__ vlen, float* __restrict__ out)
{
    __shared__ float s_p[8 * NK];        // 16 KB

    int blk = blockIdx.x;
    int b = blk & 15, qt = blk >> 4;     // qt 0..15 (8 q each)
    int q0 = qt * 8;
    int t = threadIdx.x;

    int nv = vlen[b];
    nv = max(1, min(NK, nv));
    int nv8 = (nv + 7) & ~7;

    const f32x4* Pv = (const f32x4*)(P + ((size_t)b * NQ + q0) * NK);
#pragma unroll
    for (int r = 0; r < 4; ++r)
        ((f32x4*)s_p)[t + r * 256] = Pv[t + r * 256];
    __syncthreads();

    int lane = t & 63, w = t >> 6;
    int qa = w * 2, qb = qa + 1;
    const float* pa = &s_p[qa * NK];
    const float* pb = &s_p[qb * NK];

    // row sums (zeros beyond nv included -> exact)
    f32x4 sa0 = *(const f32x4*)(pa + lane * 8);
    f32x4 sa1 = *(const f32x4*)(pa + lane * 8 + 4);
    f32x4 sb0 = *(const f32x4*)(pb + lane * 8);
    f32x4 sb1 = *(const f32x4*)(pb + lane * 8 + 4);
    float sa = ((sa0[0] + sa0[1]) + (sa0[2] + sa0[3])) +
               ((sa1[0] + sa1[1]) + (sa1[2] + sa1[3]));
    float sb = ((sb0[0] + sb0[1]) + (sb0[2] + sb0[3])) +
               ((sb1[0] + sb1[1]) + (sb1[2] + sb1[3]));
#pragma unroll
    for (int off = 32; off; off >>= 1) {
        sa += __shfl_xor(sa, off);
        sb += __shfl_xor(sb, off);
    }
    float ra = 1.0f / sa, rb = 1.0f / sb;

    int dv0 = lane * 2;
    const float* Vb = V + (size_t)b * NK * NDV + dv0;
    float a0 = 0.f, a1 = 0.f, b0 = 0.f, b1 = 0.f;
    for (int k = 0; k < nv8; k += 8) {
        f32x4 PA0 = *(const f32x4*)(pa + k);        // LDS broadcasts
        f32x4 PA1 = *(const f32x4*)(pa + k + 4);
        f32x4 PB0 = *(const f32x4*)(pb + k);
        f32x4 PB1 = *(const f32x4*)(pb + k + 4);
        f32x2 v0 = *(const f32x2*)(Vb + (size_t)(k + 0) * NDV);
        f32x2 v1 = *(const f32x2*)(Vb + (size_t)(k + 1) * NDV);
        f32x2 v2 = *(const f32x2*)(Vb + (size_t)(k + 2) * NDV);
        f32x2 v3 = *(const f32x2*)(Vb + (size_t)(k + 3) * NDV);
        f32x2 v4 = *(const f32x2*)(Vb + (size_t)(k + 4) * NDV);
        f32x2 v5 = *(const f32x2*)(Vb + (size_t)(k + 5) * NDV);
        f32x2 v6 = *(const f32x2*)(Vb + (size_t)(k + 6) * NDV);
        f32x2 v7 = *(const f32x2*)(Vb + (size_t)(k + 7) * NDV);
        a0 = fmaf(PA0[0], v0[0], a0); a1 = fmaf(PA0[0], v0[1], a1);
        b0 = fmaf(PB0[0], v0[0], b0); b1 = fmaf(PB0[0], v0[1], b1);
        a0 = fmaf(PA0[1], v1[0], a0); a1 = fmaf(PA0[1], v1[1], a1);
        b0 = fmaf(PB0[1], v1[0], b0); b1 = fmaf(PB0[1], v1[1], b1);
        a0 = fmaf(PA0[2], v2[0], a0); a1 = fmaf(PA0[2], v2[1], a1);
        b0 = fmaf(PB0[2], v2[0], b0); b1 = fmaf(PB0[2], v2[1], b1);
        a0 = fmaf(PA0[3], v3[0], a0); a1 = fmaf(PA0[3], v3[1], a1);
        b0 = fmaf(PB0[3], v3[0], b0); b1 = fmaf(PB0[3], v3[1], b1);
        a0 = fmaf(PA1[0], v4[0], a0); a1 = fmaf(PA1[0], v4[1], a1);
        b0 = fmaf(PB1[0], v4[0], b0); b1 = fmaf(PB1[0], v4[1], b1);
        a0 = fmaf(PA1[1], v5[0], a0); a1 = fmaf(PA1[1], v5[1], a1);
        b0 = fmaf(PB1[1], v5[0], b0); b1 = fmaf(PB1[1], v5[1], b1);
        a0 = fmaf(PA1[2], v6[0], a0); a1 = fmaf(PA1[2], v6[1], a1);
        b0 = fmaf(PB1[2], v6[0], b0); b1 = fmaf(PB1[2], v6[1], b1);
        a0 = fmaf(PA1[3], v7[0], a0); a1 = fmaf(PA1[3], v7[1], a1);
        b0 = fmaf(PB1[3], v7[0], b0); b1 = fmaf(PB1[3], v7[1], b1);
    }
    size_t oa = ((size_t)b * NQ + q0 + qa) * NDV + dv0;
    size_t ob = ((size_t)b * NQ + q0 + qb) * NDV + dv0;
    f32x2 Oa = {a0 * ra, a1 * ra};
    f32x2 Ob = {b0 * rb, b1 * rb};
    *(f32x2*)&out[oa] = Oa;
    *(f32x2*)&out[ob] = Ob;
}

extern "C" void kernel_launch(void* const* d_in, const int* in_sizes, int n_in,
                              void* d_out, int out_size, void* d_ws, size_t ws_size,
                              hipStream_t stream) {
    const float* q  = (const float*)d_in[0];  // (16,128,128) f32
    const float* ks = (const float*)d_in[1];  // (16,512,128) f32
    const float* vs = (const float*)d_in[2];  // (16,512,128) f32
    const int*   vl = (const int*)d_in[3];    // (16,) i32
    const float* wq = (const float*)d_in[4];  // (128,128) f32
    const float* wk = (const float*)d_in[5];  // (128,128) f32
    const float* wv = (const float*)d_in[6];  // (128,) f32

    // ws layout (~9.3 MB)
    float* Eq = (float*)d_ws;                     // 2048*128
    float* Ek = Eq + 2048 * 128;                  // 8192*128
    float* P  = Ek + (size_t)8192 * 128;          // 16*128*512
    float* w2 = P + (size_t)NB * NQ * NK;         // 128
    short* pqh = (short*)(w2 + 128);              // 4 x 16384 bf16 frags
    short* pql = pqh + 16384;
    short* pkh = pql + 16384;
    short* pkl = pkh + 16384;

    wsplit_kernel<<<16, 256, 0, stream>>>(wq, wk, wv, pqh, pql, pkh, pkl, w2);
    proj_kernel<<<640, 256, 0, stream>>>(q, ks, pqh, pql, pkh, pkl, Eq, Ek);
    score_kernel<<<512, 512, 0, stream>>>(Eq, Ek, vl, w2, P);
    av_kernel<<<256, 256, 0, stream>>>(P, vs, vl, (float*)d_out);
}